// Round 3
// baseline (2126.637 us; speedup 1.0000x reference)
//
#include <hip/hip_runtime.h>
#include <cstdint>
#include <cstddef>

#define BN 64
#define TN 512
#define DN 256
#define UN 256
#define NC 768            // 3*UN, order: r | z | h

__device__ __forceinline__ float sigm(float x) {
  return 1.0f / (1.0f + __expf(-x));
}
__device__ __forceinline__ float tanh_fast(float x) {
  float e = __expf(-2.0f * x);
  return 2.0f / (1.0f + e) - 1.0f;
}

// ---------------- kernel 0: concat weights + biases ----------------
__global__ __launch_bounds__(256) void build_wcat(
    const float* __restrict__ Wr, const float* __restrict__ Wz, const float* __restrict__ Wh,
    const float* __restrict__ br, const float* __restrict__ bz, const float* __restrict__ bh,
    float* __restrict__ wcat, float* __restrict__ bias)
{
  int idx = blockIdx.x * 256 + threadIdx.x;
  if (idx < DN * NC) {
    int k = idx / NC, c = idx % NC;
    float v;
    if (c < 256)      v = Wr[k * UN + c];
    else if (c < 512) v = Wz[k * UN + (c - 256)];
    else              v = Wh[k * UN + (c - 512)];
    wcat[idx] = v;
  }
  if (idx < NC) {
    bias[idx] = (idx < 256) ? br[idx] : ((idx < 512) ? bz[idx - 256] : bh[idx - 512]);
  }
}

// ---------------- kernel 1: P = X @ Wcat + bias  (fp32, LDS-tiled) ----------------
__global__ __launch_bounds__(256) void gemm_xw(
    const float* __restrict__ X, const float* __restrict__ Wc,
    const float* __restrict__ bias, float* __restrict__ P)
{
  __shared__ float As[32][68];
  __shared__ float Bs[32][64];
  const int tid = threadIdx.x;
  const int m0 = blockIdx.x * 64;
  const int n0 = blockIdx.y * 64;
  const int ty = tid >> 4, tx = tid & 15;
  float acc[4][4] = {};

  const int ar = tid >> 3;
  const int ak = (tid & 7) * 4;
  const int bk = tid >> 4;
  const int bn = (tid & 15) * 4;

  for (int k0 = 0; k0 < DN; k0 += 32) {
    float4 a0 = *(const float4*)(X + (size_t)(m0 + ar) * DN + k0 + ak);
    float4 a1 = *(const float4*)(X + (size_t)(m0 + 32 + ar) * DN + k0 + ak);
    As[ak + 0][ar] = a0.x; As[ak + 1][ar] = a0.y; As[ak + 2][ar] = a0.z; As[ak + 3][ar] = a0.w;
    As[ak + 0][32 + ar] = a1.x; As[ak + 1][32 + ar] = a1.y; As[ak + 2][32 + ar] = a1.z; As[ak + 3][32 + ar] = a1.w;
    *(float4*)&Bs[bk][bn]      = *(const float4*)(Wc + (size_t)(k0 + bk) * NC + n0 + bn);
    *(float4*)&Bs[bk + 16][bn] = *(const float4*)(Wc + (size_t)(k0 + bk + 16) * NC + n0 + bn);
    __syncthreads();
#pragma unroll
    for (int kk = 0; kk < 32; kk++) {
      float4 av = *(const float4*)&As[kk][ty * 4];
      float4 bv = *(const float4*)&Bs[kk][tx * 4];
      acc[0][0] += av.x * bv.x; acc[0][1] += av.x * bv.y; acc[0][2] += av.x * bv.z; acc[0][3] += av.x * bv.w;
      acc[1][0] += av.y * bv.x; acc[1][1] += av.y * bv.y; acc[1][2] += av.y * bv.z; acc[1][3] += av.y * bv.w;
      acc[2][0] += av.z * bv.x; acc[2][1] += av.z * bv.y; acc[2][2] += av.z * bv.z; acc[2][3] += av.z * bv.w;
      acc[3][0] += av.w * bv.x; acc[3][1] += av.w * bv.y; acc[3][2] += av.w * bv.z; acc[3][3] += av.w * bv.w;
    }
    __syncthreads();
  }
  float4 bb = *(const float4*)(bias + n0 + tx * 4);
#pragma unroll
  for (int i = 0; i < 4; i++) {
    float4 o;
    o.x = acc[i][0] + bb.x; o.y = acc[i][1] + bb.y;
    o.z = acc[i][2] + bb.z; o.w = acc[i][3] + bb.w;
    *(float4*)(P + (size_t)(m0 + ty * 4 + i) * NC + n0 + tx * 4) = o;
  }
}

// ---------------- kernel 2: recurrence, 4 blocks per batch (column split) -------
// grid = 256 blocks: b = blockIdx&63, j = blockIdx>>6 owns cols [64j, 64j+64).
// thread = (q = tid>>6 in [0,8), c = tid&63): weight slice k in [32q,32q+32), col 64j+c
// in VGPRs (3 x 32 floats). Cross-block per active step: exchange rs (round 1) and
// h (round 2) via agent-scope atomics + monotonic flags (memset 0 at launch).
__global__ __launch_bounds__(512, 2) void recurrent_kernel(
    const float* __restrict__ P,
    const float* __restrict__ Ur, const float* __restrict__ Uz, const float* __restrict__ Uh,
    const int* __restrict__ dep, const int* __restrict__ mask,
    const float* __restrict__ init,
    float* __restrict__ out,
    float* __restrict__ buf_s, float* __restrict__ buf_pr, float* __restrict__ buf_pz,
    float* __restrict__ rs_comm, float* __restrict__ h_comm,
    int* __restrict__ flag1, int* __restrict__ flag2)
{
  const int bid = blockIdx.x;
  const int b = bid & 63;
  const int j = bid >> 6;          // peers {b, b+64, b+128, b+192}: same XCD under %8
  const int tid = threadIdx.x;
  const int q = tid >> 6;          // wave index (wave-uniform)
  const int c = tid & 63;
  const int u = 64 * j + c;        // global output column

  // --- weight slices in registers ---
  float wh[32], wr[32], wz[32];
#pragma unroll
  for (int kk = 0; kk < 32; kk++) {
    int k = 32 * q + kk;
    wh[kk] = Uh[(size_t)k * UN + u];
    wr[kk] = Ur[(size_t)k * UN + u];
    wz[kk] = Uz[(size_t)k * UN + u];
  }

  __shared__ float rs_full[256], h_full[256];
  __shared__ float partA[8][64], partB[8][64];
  __shared__ float hs_l[64], zs_l[64], xh_l[64];
  __shared__ float prev_h[64], prev_pr[64], prev_pz[64];
  __shared__ float is_[4][64], ipr[4][64], ipz[4][64];
  __shared__ float ifull[256];
  __shared__ int eff[TN];
  __shared__ int mloc[TN];
  __shared__ int deploc[TN * 3];

  for (int i = tid; i < TN; i += 512) mloc[i] = mask[b * TN + i];
  for (int i = tid; i < TN * 3; i += 512) deploc[i] = dep[i];
  if (tid < 64) { prev_h[c] = 0.0f; prev_pr[c] = 0.0f; prev_pz[c] = 0.0f; }
  __syncthreads();

  // prologue: initial-state projections (full init vector from global input; local)
#pragma unroll 1
  for (int i = 0; i < 4; i++) {
    if (tid < 256) ifull[tid] = init[((size_t)i * BN + b) * UN + tid];
    __syncthreads();
    float ar = 0.0f, az = 0.0f;
#pragma unroll
    for (int kk = 0; kk < 32; kk++) {
      float hk = ifull[32 * q + kk];
      ar = fmaf(hk, wr[kk], ar);
      az = fmaf(hk, wz[kk], az);
    }
    partA[q][c] = ar; partB[q][c] = az;
    __syncthreads();
    if (tid < 64) {
      float sr = 0.0f, sz = 0.0f;
#pragma unroll
      for (int qq = 0; qq < 8; qq++) { sr += partA[qq][c]; sz += partB[qq][c]; }
      ipr[i][c] = sr; ipz[i][c] = sz; is_[i][c] = ifull[u];
    }
    __syncthreads();
  }

  const size_t outB = (size_t)b * TN * UN;
  const size_t pB   = (size_t)b * TN * NC;
  const size_t bufB = (size_t)b * TN * UN;
  float* my_rs = rs_comm + ((size_t)b * 4 + j) * 64;
  float* my_h  = h_comm  + ((size_t)b * 4 + j) * 64;
  int* f1 = flag1 + b * 4;
  int* f2 = flag2 + b * 4;

#pragma unroll 1
  for (int t = 0; t < TN; t++) {
    if (mloc[t] == 0) {
      if (tid < 64) out[outB + (size_t)t * UN + u] = 0.0f;
      if (tid == 0) eff[t] = (t == 0) ? -1 : eff[t - 1];
      __syncthreads();
      continue;
    }
    // ---- gates + own rs (tid < 64) ----
    if (tid < 64) {
      float s0, s1, s2, s3, pr0, pr1, pr2, pr3, pz0, pz1, pz2, pz3;
      if (t == 0) {
        s0 = is_[0][c]; s1 = is_[1][c]; s2 = is_[2][c]; s3 = is_[3][c];
        pr0 = ipr[0][c]; pr1 = ipr[1][c]; pr2 = ipr[2][c]; pr3 = ipr[3][c];
        pz0 = ipz[0][c]; pz1 = ipz[1][c]; pz2 = ipz[2][c]; pz3 = ipz[3][c];
      } else {
        s0 = prev_h[c]; pr0 = prev_pr[c]; pz0 = prev_pz[c];
        int src1 = eff[deploc[(t - 1) * 3 + 0]];
        int src2 = eff[deploc[(t - 1) * 3 + 1]];
        int src3 = eff[deploc[(t - 1) * 3 + 2]];
        if (src1 < 0) { s1 = 0; pr1 = 0; pz1 = 0; }
        else { size_t a = bufB + (size_t)src1 * UN + u; s1 = buf_s[a]; pr1 = buf_pr[a]; pz1 = buf_pz[a]; }
        if (src2 < 0) { s2 = 0; pr2 = 0; pz2 = 0; }
        else { size_t a = bufB + (size_t)src2 * UN + u; s2 = buf_s[a]; pr2 = buf_pr[a]; pz2 = buf_pz[a]; }
        if (src3 < 0) { s3 = 0; pr3 = 0; pz3 = 0; }
        else { size_t a = bufB + (size_t)src3 * UN + u; s3 = buf_s[a]; pr3 = buf_pr[a]; pz3 = buf_pz[a]; }
      }
      float xr = P[pB + (size_t)t * NC + u];
      float xz = P[pB + (size_t)t * NC + 256 + u];
      xh_l[c] = P[pB + (size_t)t * NC + 512 + u];
      float r0 = sigm(xr + pr0), r1 = sigm(xr + pr1), r2 = sigm(xr + pr2), r3 = sigm(xr + pr3);
      float rsv = r0 * s0 + r1 * s1 + r2 * s2 + r3 * s3;
      hs_l[c] = (s0 + s1) + (s2 + s3);
      zs_l[c] = sigm(xz + ((pz0 + pz1) + (pz2 + pz3)));
      rs_full[u] = rsv;
      __hip_atomic_store(&my_rs[c], rsv, __ATOMIC_RELAXED, __HIP_MEMORY_SCOPE_AGENT);
    }
    __syncthreads();   // drains vmcnt: rs_comm stores visible at coherent point
    if (tid == 0) __hip_atomic_store(&f1[j], t + 1, __ATOMIC_RELEASE, __HIP_MEMORY_SCOPE_AGENT);
    if (tid < 3) {
      int p = (j + 1 + tid) & 3;
      while (__hip_atomic_load(&f1[p], __ATOMIC_RELAXED, __HIP_MEMORY_SCOPE_AGENT) < t + 1) {}
    }
    __syncthreads();
    if (tid < 192) {
      int pp = (j + 1 + (tid >> 6)) & 3;
      rs_full[64 * pp + c] =
          __hip_atomic_load(&rs_comm[((size_t)b * 4 + pp) * 64 + c], __ATOMIC_RELAXED, __HIP_MEMORY_SCOPE_AGENT);
    }
    __syncthreads();
    // ---- B: hh (own cols) from full rs; weights in VGPRs ----
    {
      float a = 0.0f;
#pragma unroll
      for (int kk = 0; kk < 32; kk++) a = fmaf(rs_full[32 * q + kk], wh[kk], a);
      partA[q][c] = a;
    }
    __syncthreads();
    if (tid < 64) {
      float hh = 0.0f;
#pragma unroll
      for (int qq = 0; qq < 8; qq++) hh += partA[qq][c];
      float z = zs_l[c];
      float h = z * hs_l[c] * 0.25f + (1.0f - z) * tanh_fast(xh_l[c] + hh);
      prev_h[c] = h; h_full[u] = h;
      out[outB + (size_t)t * UN + u] = h;
      buf_s[bufB + (size_t)t * UN + u] = h;
      __hip_atomic_store(&my_h[c], h, __ATOMIC_RELAXED, __HIP_MEMORY_SCOPE_AGENT);
    }
    __syncthreads();
    if (tid == 0) __hip_atomic_store(&f2[j], t + 1, __ATOMIC_RELEASE, __HIP_MEMORY_SCOPE_AGENT);
    if (tid < 3) {
      int p = (j + 1 + tid) & 3;
      while (__hip_atomic_load(&f2[p], __ATOMIC_RELAXED, __HIP_MEMORY_SCOPE_AGENT) < t + 1) {}
    }
    __syncthreads();
    if (tid < 192) {
      int pp = (j + 1 + (tid >> 6)) & 3;
      h_full[64 * pp + c] =
          __hip_atomic_load(&h_comm[((size_t)b * 4 + pp) * 64 + c], __ATOMIC_RELAXED, __HIP_MEMORY_SCOPE_AGENT);
    }
    __syncthreads();
    // ---- D: project new h through Ur|Uz (own cols) ----
    {
      float ar = 0.0f, az = 0.0f;
#pragma unroll
      for (int kk = 0; kk < 32; kk++) {
        float hk = h_full[32 * q + kk];
        ar = fmaf(hk, wr[kk], ar);
        az = fmaf(hk, wz[kk], az);
      }
      partA[q][c] = ar; partB[q][c] = az;
    }
    __syncthreads();
    if (tid < 64) {
      float sr = 0.0f, sz = 0.0f;
#pragma unroll
      for (int qq = 0; qq < 8; qq++) { sr += partA[qq][c]; sz += partB[qq][c]; }
      prev_pr[c] = sr; prev_pz[c] = sz;
      size_t a = bufB + (size_t)t * UN + u;
      buf_pr[a] = sr; buf_pz[a] = sz;
    }
    if (tid == 0) eff[t] = t;
    __syncthreads();
  }

  // epilogue: last_out, last_state
  if (tid < 64) {
    float lst = prev_h[c];
    out[(size_t)BN * TN * UN + (size_t)b * UN + u] = mloc[TN - 1] ? lst : 0.0f;
    out[(size_t)BN * TN * UN + (size_t)BN * UN + (size_t)b * UN + u] = lst;
  }
}

extern "C" void kernel_launch(void* const* d_in, const int* in_sizes, int n_in,
                              void* d_out, int out_size, void* d_ws, size_t ws_size,
                              hipStream_t stream) {
  const float* inputs       = (const float*)d_in[0];
  const int*   dependencies = (const int*)d_in[1];
  const int*   mask         = (const int*)d_in[2];
  const float* initial      = (const float*)d_in[3];
  const float* Wz = (const float*)d_in[4];
  const float* Wr = (const float*)d_in[5];
  const float* Wh = (const float*)d_in[6];
  const float* Uz = (const float*)d_in[7];
  const float* Ur = (const float*)d_in[8];
  const float* Uh = (const float*)d_in[9];
  const float* bz = (const float*)d_in[10];
  const float* br = (const float*)d_in[11];
  const float* bh = (const float*)d_in[12];

  float* out = (float*)d_out;
  float* ws  = (float*)d_ws;

  int*   flag1   = (int*)ws;                             // 64*4
  int*   flag2   = flag1 + 256;                          // 64*4
  float* rs_comm = ws + 512;                             // 64*4*64
  float* h_comm  = rs_comm + (size_t)BN * 4 * 64;        // 64*4*64
  float* wcat    = h_comm + (size_t)BN * 4 * 64;         // 256*768
  float* bias    = wcat + (size_t)DN * NC;               // 768
  float* precomp = bias + NC;                            // B*T*768
  float* buf_s   = precomp + (size_t)BN * TN * NC;       // B*T*256 each
  float* buf_pr  = buf_s + (size_t)BN * TN * UN;
  float* buf_pz  = buf_pr + (size_t)BN * TN * UN;

  // flags must start at 0 every launch (graph-capturable async memset)
  hipMemsetAsync(flag1, 0, 512 * sizeof(int), stream);

  build_wcat<<<(DN * NC + 255) / 256, 256, 0, stream>>>(Wr, Wz, Wh, br, bz, bh, wcat, bias);
  gemm_xw<<<dim3(BN * TN / 64, NC / 64), 256, 0, stream>>>(inputs, wcat, bias, precomp);
  recurrent_kernel<<<256, 512, 0, stream>>>(precomp, Ur, Uz, Uh, dependencies, mask, initial,
                                            out, buf_s, buf_pr, buf_pz,
                                            rs_comm, h_comm, flag1, flag2);
}